// Round 8
// baseline (846.318 us; speedup 1.0000x reference)
//
#include <hip/hip_runtime.h>

typedef __attribute__((ext_vector_type(16))) float    f32x16;
typedef __attribute__((ext_vector_type(8)))  short    bf16x8;
typedef __attribute__((ext_vector_type(2)))  int      i32x2;
typedef __attribute__((ext_vector_type(16))) unsigned u32x16;
typedef __attribute__((ext_vector_type(4)))  unsigned u32x4;

// compiler-managed permlane32_swap: a' = {a.lo, b.lo}, b' = {a.hi, b.hi}
__device__ __forceinline__ void laneswap(unsigned& a, unsigned& b){
    i32x2 r = __builtin_amdgcn_permlane32_swap((int)a, (int)b, false, false);
    a = (unsigned)r[0]; b = (unsigned)r[1];
}

// pack two floats into {bf16(lo), bf16(hi)<<16}, RNE
__device__ __forceinline__ unsigned cvtpk(float lo, float hi){
    unsigned ul = __float_as_uint(lo);
    unsigned uh = __float_as_uint(hi);
    ul = (ul + 0x7FFFu + ((ul >> 16) & 1u)) >> 16;
    uh = (uh + 0x7FFFu + ((uh >> 16) & 1u)) & 0xFFFF0000u;
    return ul | uh;
}

__device__ __forceinline__ float halfsum(float v){   // v + (other 32-lane half)
    return v + __shfl_xor(v, 32, 64);
}

__device__ __forceinline__ float fast_tanh(float v){
    float vc = fminf(v, 15.0f);
    float e  = __expf(vc + vc);
    float r  = __builtin_amdgcn_rcpf(e + 1.0f);
    return (e - 1.0f) * r;
}

// SSA-clean B-operand construction (no union, no memory round-trip)
__device__ __forceinline__ bf16x8 mkb(unsigned a, unsigned b, unsigned c, unsigned d){
    u32x4 t; t[0]=a; t[1]=b; t[2]=c; t[3]=d;
    return __builtin_bit_cast(bf16x8, t);
}

__device__ __forceinline__ f32x16 zf(){
    f32x16 z;
#pragma unroll
    for (int i=0;i<16;++i) z[i]=0.f;
    return z;
}

__device__ __forceinline__ bf16x8 ldA(const unsigned short* p){
    return *(const bf16x8*)p;   // 16B-aligned ds_read_b128
}

__device__ __forceinline__ f32x16 MF(bf16x8 a, bf16x8 b, f32x16 c){
    return __builtin_amdgcn_mfma_f32_32x32x16_bf16(a, b, c, 0, 0, 0);
}

__device__ __forceinline__ unsigned short tob(float x){
    unsigned u = __float_as_uint(x);
    return (unsigned short)((u + 0x7FFFu + ((u >> 16) & 1u)) >> 16);
}

struct alignas(16) SLDS {
    unsigned short cw2T[128*136];   // [i][k] = cw2[k][i]; col 128 = cb2
    unsigned short fwdWT[4][64*72]; // hw2..5: [i][k] = W[k][i]; col 64 = bias
    unsigned short bwdW[4][64*72];  // hw2..5 row-major [k_out][f]
    unsigned short hw1T[64*16];     // [i][k]: k0-3 = hw1[k][i], k4 = hb1[i]
    float c1pack[128*4];            // {cw1[0][k], cw1[1][k], cb1[k], 0}
    float cw3p[128*2];
    float hw1c[64*4];               // {hw1[0][f], hw1[1][f], hw1[2][f], hw1[3][f]}
    float hw6v[64];
    float cb3v[2];
    float pad[30];                  // tail guard (h=1 bias-step overreads see x0 operands)
};
// sizeof = 115072 B = 7192 uint4

// fwd layer 64->64: D = WT x B over 4 K-steps + bias K-step
__device__ __forceinline__ void fwd64(const unsigned short* W, u32x16 pkin,
                                      f32x16& A0, f32x16& A1, int col, int h){
    A0 = zf(); A1 = zf();
#pragma unroll
    for (int st=0; st<4; ++st){
        unsigned u0 = pkin[4*st+0], u2 = pkin[4*st+2];
        unsigned u1 = pkin[4*st+1], u3 = pkin[4*st+3];
        laneswap(u0, u2);
        laneswap(u1, u3);
        bf16x8 bv = mkb(u0,u1,u2,u3);
        const unsigned short* p0 = W + col*72 + st*16 + h*8;
        A0 = MF(ldA(p0),         bv, A0);
        A1 = MF(ldA(p0 + 32*72), bv, A1);
    }
    bf16x8 bb = mkb(h ? 0u : 0x3F80u, 0u, 0u, 0u);
    const unsigned short* pb = W + col*72 + 64 + h*8;
    A0 = MF(ldA(pb),         bb, A0);
    A1 = MF(ldA(pb + 32*72), bb, A1);
}

__device__ __forceinline__ void bwd64(const unsigned short* W, u32x16 pkin,
                                      f32x16& A0, f32x16& A1, int col, int h){
    A0 = zf(); A1 = zf();
#pragma unroll
    for (int st=0; st<4; ++st){
        unsigned u0 = pkin[4*st+0], u2 = pkin[4*st+2];
        unsigned u1 = pkin[4*st+1], u3 = pkin[4*st+3];
        laneswap(u0, u2);
        laneswap(u1, u3);
        bf16x8 bv = mkb(u0,u1,u2,u3);
        const unsigned short* p0 = W + col*72 + st*16 + h*8;
        A0 = MF(ldA(p0),         bv, A0);
        A1 = MF(ldA(p0 + 32*72), bv, A1);
    }
}

__device__ __forceinline__ u32x16 relu_pk(const f32x16& z0, const f32x16& z1, unsigned& mask){
    u32x16 pk;
    unsigned m = 0u;
#pragma unroll
    for (int i=0;i<8;++i){
        float a = z0[2*i], b = z0[2*i+1];
        if (a > 0.f) m |= 1u << (2*i);   else a = 0.f;
        if (b > 0.f) m |= 1u << (2*i+1); else b = 0.f;
        pk[i] = cvtpk(a, b);
    }
#pragma unroll
    for (int i=0;i<8;++i){
        float a = z1[2*i], b = z1[2*i+1];
        if (a > 0.f) m |= 1u << (16+2*i);   else a = 0.f;
        if (b > 0.f) m |= 1u << (16+2*i+1); else b = 0.f;
        pk[8+i] = cvtpk(a, b);
    }
    mask = m;
    return pk;
}

__device__ __forceinline__ u32x16 tanh_pk(const f32x16& z0, const f32x16& z1){
    u32x16 pk;
#pragma unroll
    for (int i=0;i<8;++i) pk[i]   = cvtpk(fast_tanh(z0[2*i]), fast_tanh(z0[2*i+1]));
#pragma unroll
    for (int i=0;i<8;++i) pk[8+i] = cvtpk(fast_tanh(z1[2*i]), fast_tanh(z1[2*i+1]));
    return pk;
}

__device__ __forceinline__ u32x16 repack_pk(const f32x16& g0, const f32x16& g1){
    u32x16 pk;
#pragma unroll
    for (int i=0;i<8;++i) pk[i]   = cvtpk(g0[2*i], g0[2*i+1]);
#pragma unroll
    for (int i=0;i<8;++i) pk[8+i] = cvtpk(g1[2*i], g1[2*i+1]);
    return pk;
}

// coupling net 2->125(relu)->125(tanh)->2, batch-in-lane-column MFMA form
__device__ __forceinline__ float2 couple(float u0f, float u1f, const SLDS* s, int col, int h){
    f32x16 c0 = zf(), c1 = zf(), c2 = zf(), c3 = zf();
#pragma unroll
    for (int st=0; st<8; ++st){
        float hv[8];
#pragma unroll
        for (int e=0; e<8; ++e){
            int k = st*16 + h*8 + e;
            float4 cc = *(const float4*)&s->c1pack[4*k];
            hv[e] = fmaxf(fmaf(u1f, cc.y, fmaf(u0f, cc.x, cc.z)), 0.f);
        }
        bf16x8 bv = mkb(cvtpk(hv[0],hv[1]), cvtpk(hv[2],hv[3]),
                        cvtpk(hv[4],hv[5]), cvtpk(hv[6],hv[7]));
        const unsigned short* p = s->cw2T + col*136 + st*16 + h*8;
        c0 = MF(ldA(p),          bv, c0);
        c1 = MF(ldA(p + 32*136), bv, c1);
        c2 = MF(ldA(p + 64*136), bv, c2);
        c3 = MF(ldA(p + 96*136), bv, c3);
    }
    {   // bias K-step: B = {1,0,...} on h=0; A cols 128.. hold cb2
        bf16x8 bb = mkb(h ? 0u : 0x3F80u, 0u, 0u, 0u);
        const unsigned short* p = s->cw2T + col*136 + 128 + h*8;
        c0 = MF(ldA(p),          bb, c0);
        c1 = MF(ldA(p + 32*136), bb, c1);
        c2 = MF(ldA(p + 64*136), bb, c2);
        c3 = MF(ldA(p + 96*136), bb, c3);
    }
    float o0 = 0.f, o1 = 0.f;
#define CDOT(CA, T) \
    _Pragma("unroll") \
    for (int r=0; r<16; ++r){ \
        float t = fast_tanh(CA[r]); \
        int f = (T)*32 + (r>>2)*8 + (r&3) + h*4; \
        float2 wv = *(const float2*)&s->cw3p[2*f]; \
        o0 = fmaf(t, wv.x, o0); o1 = fmaf(t, wv.y, o1); }
    CDOT(c0,0) CDOT(c1,1) CDOT(c2,2) CDOT(c3,3)
#undef CDOT
    o0 = halfsum(o0);
    o1 = halfsum(o1);
    return make_float2(o0 + s->cb3v[0], o1 + s->cb3v[1]);
}

// one-shot: build the SLDS image in global workspace
__global__ void pack_ws(const float* __restrict__ cw1, const float* __restrict__ cb1,
                        const float* __restrict__ cw2, const float* __restrict__ cb2,
                        const float* __restrict__ cw3, const float* __restrict__ cb3,
                        const float* __restrict__ hw1, const float* __restrict__ hb1,
                        const float* __restrict__ hw2, const float* __restrict__ hb2,
                        const float* __restrict__ hw3, const float* __restrict__ hb3,
                        const float* __restrict__ hw4, const float* __restrict__ hb4,
                        const float* __restrict__ hw5, const float* __restrict__ hb5,
                        const float* __restrict__ hw6, SLDS* __restrict__ g){
    const int tid = blockIdx.x*256 + threadIdx.x;
    const int NT  = 64*256;
    for (int i = tid; i < 128*136; i += NT){
        int r = i/136, k = i%136;
        float v = 0.f;
        if (k < 125 && r < 125) v = cw2[k*125 + r];
        else if (k == 128 && r < 125) v = cb2[r];
        g->cw2T[i] = tob(v);
    }
#pragma unroll
    for (int m=0; m<4; ++m){
        const float* w = (m==0)?hw2:(m==1)?hw3:(m==2)?hw4:hw5;
        const float* b = (m==0)?hb2:(m==1)?hb3:(m==2)?hb4:hb5;
        for (int i = tid; i < 64*72; i += NT){
            int r = i/72, k = i%72;
            g->fwdWT[m][i] = tob((k<64) ? w[k*64 + r] : ((k==64) ? b[r] : 0.f));
            g->bwdW[m][i]  = tob((k<64) ? w[r*64 + k] : 0.f);
        }
    }
    for (int i = tid; i < 64*16; i += NT){
        int r = i/16, k = i%16;
        g->hw1T[i] = tob((k<4) ? hw1[k*64 + r] : ((k==4) ? hb1[r] : 0.f));
    }
    for (int k = tid; k < 128; k += NT){
        bool in = k < 125;
        g->c1pack[4*k+0] = in ? cw1[k]     : 0.f;
        g->c1pack[4*k+1] = in ? cw1[125+k] : 0.f;
        g->c1pack[4*k+2] = in ? cb1[k]     : 0.f;
        g->c1pack[4*k+3] = 0.f;
        g->cw3p[2*k+0]   = in ? cw3[2*k]   : 0.f;
        g->cw3p[2*k+1]   = in ? cw3[2*k+1] : 0.f;
    }
    for (int f = tid; f < 64; f += NT){
        g->hw1c[4*f+0] = hw1[f];
        g->hw1c[4*f+1] = hw1[64+f];
        g->hw1c[4*f+2] = hw1[128+f];
        g->hw1c[4*f+3] = hw1[192+f];
        g->hw6v[f] = hw6[f];
    }
    if (tid == 0){ g->cb3v[0] = cb3[0]; g->cb3v[1] = cb3[1]; }
    for (int i = tid; i < 30; i += NT) g->pad[i] = 0.f;
}

__global__ __launch_bounds__(512, 2) void pnn_mfma(
    const float* __restrict__ x, const SLDS* __restrict__ g,
    const float* __restrict__ S, const float* __restrict__ dt_q,
    const float* __restrict__ dt_p, const float* __restrict__ alpha_p,
    float* __restrict__ out)
{
    __shared__ SLDS s;
    const int tid = threadIdx.x;

    // stage SLDS image (16B copies)
    {
        const uint4* src = (const uint4*)g;
        uint4* dst = (uint4*)&s;
        for (int i = tid; i < (int)(sizeof(SLDS)/16); i += 512) dst[i] = src[i];
    }
    __syncthreads();

    const int lane = tid & 63;
    const int wv   = tid >> 6;
    const int col  = lane & 31;
    const int h    = lane >> 5;
    const int row  = blockIdx.x * 256 + wv*32 + col;

    float4 xv = ((const float4*)x)[row];

    float2 cpl = couple(xv.x, xv.y, &s, col, h);
    float th0 = xv.x, th1 = xv.y, th2 = xv.z + cpl.x, th3 = xv.w + cpl.y;

    // ---- H forward L1 (theta K=4 + bias slot, one K-step) ----
    f32x16 z0, z1;
    {
        bf16x8 b1 = mkb(h ? 0u : cvtpk(th0, th1),
                        h ? 0u : cvtpk(th2, th3),
                        h ? 0u : 0x3F80u, 0u);
        const unsigned short* p = s.hw1T + col*16 + h*8;
        z0 = MF(ldA(p),         b1, zf());
        z1 = MF(ldA(p + 32*16), b1, zf());
    }

    unsigned m1, m2;
    u32x16 pkA = relu_pk(z0, z1, m1);

    fwd64(s.fwdWT[0], pkA, z0, z1, col, h);      // L2
    pkA = relu_pk(z0, z1, m2);

    fwd64(s.fwdWT[1], pkA, z0, z1, col, h);      // L3
    u32x16 pk3 = tanh_pk(z0, z1);

    fwd64(s.fwdWT[2], pk3, z0, z1, col, h);      // L4
    u32x16 pk4 = tanh_pk(z0, z1);

    fwd64(s.fwdWT[3], pk4, z0, z1, col, h);      // L5
    // g5 = hw6 ⊙ (1 - tanh(z5)^2)
    u32x16 pkG;
#define G5T(ZZ, T) \
    _Pragma("unroll") \
    for (int q=0; q<4; ++q){ \
        float4 w6 = *(const float4*)&s.hw6v[(T)*32 + q*8 + h*4]; \
        float t0 = fast_tanh(ZZ[4*q+0]); float g0v = w6.x * fmaf(-t0,t0,1.f); \
        float t1 = fast_tanh(ZZ[4*q+1]); float g1v = w6.y * fmaf(-t1,t1,1.f); \
        float t2 = fast_tanh(ZZ[4*q+2]); float g2v = w6.z * fmaf(-t2,t2,1.f); \
        float t3 = fast_tanh(ZZ[4*q+3]); float g3v = w6.w * fmaf(-t3,t3,1.f); \
        pkG[(T)*8 + 2*q]   = cvtpk(g0v, g1v); \
        pkG[(T)*8 + 2*q+1] = cvtpk(g2v, g3v); }
    G5T(z0, 0)
    G5T(z1, 1)
#undef G5T

    // ---- backward ----
    f32x16 g0, g1;
#define TPRIME(PK) \
    _Pragma("unroll") \
    for (int i=0;i<8;++i){ \
        float tl = __uint_as_float(PK[i] << 16); \
        float tH = __uint_as_float(PK[i] & 0xFFFF0000u); \
        g0[2*i]   *= fmaf(-tl, tl, 1.f); \
        g0[2*i+1] *= fmaf(-tH, tH, 1.f); } \
    _Pragma("unroll") \
    for (int i=0;i<8;++i){ \
        float tl = __uint_as_float(PK[8+i] << 16); \
        float tH = __uint_as_float(PK[8+i] & 0xFFFF0000u); \
        g1[2*i]   *= fmaf(-tl, tl, 1.f); \
        g1[2*i+1] *= fmaf(-tH, tH, 1.f); }

    bwd64(s.bwdW[3], pkG, g0, g1, col, h);       // g4
    TPRIME(pk4)
    pkG = repack_pk(g0, g1);

    bwd64(s.bwdW[2], pkG, g0, g1, col, h);       // g3
    TPRIME(pk3)
    pkG = repack_pk(g0, g1);

    bwd64(s.bwdW[1], pkG, g0, g1, col, h);       // g2
#pragma unroll
    for (int r=0;r<16;++r){
        if (!((m2 >> r) & 1u))      g0[r] = 0.f;
        if (!((m2 >> (16+r)) & 1u)) g1[r] = 0.f;
    }
    pkG = repack_pk(g0, g1);

    bwd64(s.bwdW[0], pkG, g0, g1, col, h);       // g1
#pragma unroll
    for (int r=0;r<16;++r){
        if (!((m1 >> r) & 1u))      g0[r] = 0.f;
        if (!((m1 >> (16+r)) & 1u)) g1[r] = 0.f;
    }
#undef TPRIME

    // dH = g1 @ hw1^T: per-lane partial over its 32 features, then cross-half add
    float dh0=0.f, dh1=0.f, dh2=0.f, dh3=0.f;
#define DHT(GG, T) \
    _Pragma("unroll") \
    for (int q=0;q<4;++q){ \
        int f0 = (T)*32 + q*8 + h*4; \
        _Pragma("unroll") \
        for (int m=0;m<4;++m){ \
            float4 wv4 = *(const float4*)&s.hw1c[4*(f0+m)]; \
            float gv = GG[4*q+m]; \
            dh0 = fmaf(gv, wv4.x, dh0); dh1 = fmaf(gv, wv4.y, dh1); \
            dh2 = fmaf(gv, wv4.z, dh2); dh3 = fmaf(gv, wv4.w, dh3); } }
    DHT(g0, 0)
    DHT(g1, 1)
#undef DHT
    dh0 = halfsum(dh0);
    dh1 = halfsum(dh1);
    dh2 = halfsum(dh2);
    dh3 = halfsum(dh3);

    // ---- epilogue ----
    float s01 = S[1] - S[4],  s02 = S[2]  - S[8],  s03 = S[3]  - S[12];
    float s10 = -s01,         s12 = S[6]  - S[9],  s13 = S[7]  - S[13];
    float s23 = S[11] - S[14];
    float s32 = -s23;

    float al = alpha_p[0], dq = dt_q[0], dp = dt_p[0];
    float r10 = th1 * s01 + th2 * s02 + th3 * s03;
    float r11 = th0 * s10 + th2 * s12 + th3 * s13;
    float r20 = th0 * s02 + th1 * s12 + th3 * s32;
    float r21 = th0 * s03 + th1 * s13 + th2 * s23;

    float dz10 =  dh2 * dq + al * r10;
    float dz11 =  dh3 * dq + al * r11;
    float dz20 = -dh0 * dp + al * r20;
    float dz21 = -dh1 * dp + al * r21;

    float p0 = th0 + 0.1f * dz10;
    float p1 = th1 + 0.1f * dz11;
    float p2 = th2 + 0.1f * dz20;
    float p3 = th3 + 0.1f * dz21;

    float2 d = couple(p0, p1, &s, col, h);

    if (h == 0)
        ((float4*)out)[row] = make_float4(p0, p1, p2 - d.x, p3 - d.y);
}

extern "C" void kernel_launch(void* const* d_in, const int* in_sizes, int n_in,
                              void* d_out, int out_size, void* d_ws, size_t ws_size,
                              hipStream_t stream) {
    (void)n_in; (void)out_size; (void)ws_size;
    const float* x   = (const float*)d_in[0];
    const float* cw1 = (const float*)d_in[1];
    const float* cb1 = (const float*)d_in[2];
    const float* cw2 = (const float*)d_in[3];
    const float* cb2 = (const float*)d_in[4];
    const float* cw3 = (const float*)d_in[5];
    const float* cb3 = (const float*)d_in[6];
    const float* hw1 = (const float*)d_in[7];
    const float* hb1 = (const float*)d_in[8];
    const float* hw2 = (const float*)d_in[9];
    const float* hb2 = (const float*)d_in[10];
    const float* hw3 = (const float*)d_in[11];
    const float* hb3 = (const float*)d_in[12];
    const float* hw4 = (const float*)d_in[13];
    const float* hb4 = (const float*)d_in[14];
    const float* hw5 = (const float*)d_in[15];
    const float* hb5 = (const float*)d_in[16];
    const float* hw6 = (const float*)d_in[17];
    const float* S   = (const float*)d_in[19];
    const float* dtq = (const float*)d_in[20];
    const float* dtp = (const float*)d_in[21];
    const float* al  = (const float*)d_in[22];
    float* out = (float*)d_out;
    SLDS* g   = (SLDS*)d_ws;
    int nrows = in_sizes[0] / 4;
    int grid  = nrows / 256;          // B = 524288 -> 2048 exact

    pack_ws<<<64, 256, 0, stream>>>(cw1, cb1, cw2, cb2, cw3, cb3, hw1, hb1,
                                    hw2, hb2, hw3, hb3, hw4, hb4, hw5, hb5, hw6, g);
    pnn_mfma<<<grid, 512, 0, stream>>>(x, g, S, dtq, dtp, al, out);
}

// Round 9
// 378.828 us; speedup vs baseline: 2.2340x; 2.2340x over previous
//
#include <hip/hip_runtime.h>

typedef __attribute__((ext_vector_type(16))) float    f32x16;
typedef __attribute__((ext_vector_type(8)))  short    bf16x8;
typedef __attribute__((ext_vector_type(2)))  int      i32x2;
typedef __attribute__((ext_vector_type(4)))  unsigned u32x4;

// compiler-managed permlane32_swap: a' = {a.lo, b.lo}, b' = {a.hi, b.hi}
__device__ __forceinline__ void laneswap(unsigned& a, unsigned& b){
    i32x2 r = __builtin_amdgcn_permlane32_swap((int)a, (int)b, false, false);
    a = (unsigned)r[0]; b = (unsigned)r[1];
}

// pack two floats into {bf16(lo), bf16(hi)<<16}, RNE
__device__ __forceinline__ unsigned cvtpk(float lo, float hi){
    unsigned ul = __float_as_uint(lo);
    unsigned uh = __float_as_uint(hi);
    ul = (ul + 0x7FFFu + ((ul >> 16) & 1u)) >> 16;
    uh = (uh + 0x7FFFu + ((uh >> 16) & 1u)) & 0xFFFF0000u;
    return ul | uh;
}

__device__ __forceinline__ float halfsum(float v){   // v + (other 32-lane half)
    return v + __shfl_xor(v, 32, 64);
}

__device__ __forceinline__ float fast_tanh(float v){
    float vc = fminf(v, 15.0f);
    float e  = __expf(vc + vc);
    float r  = __builtin_amdgcn_rcpf(e + 1.0f);
    return (e - 1.0f) * r;
}

// SSA-clean B-operand construction
__device__ __forceinline__ bf16x8 mkb(unsigned a, unsigned b, unsigned c, unsigned d){
    u32x4 t; t[0]=a; t[1]=b; t[2]=c; t[3]=d;
    return __builtin_bit_cast(bf16x8, t);
}

__device__ __forceinline__ f32x16 zf(){
    f32x16 z;
#pragma unroll
    for (int i=0;i<16;++i) z[i]=0.f;
    return z;
}

__device__ __forceinline__ bf16x8 ldA(const unsigned short* p){
    return *(const bf16x8*)p;   // 16B-aligned ds_read_b128
}

__device__ __forceinline__ f32x16 MF(bf16x8 a, bf16x8 b, f32x16 c){
    return __builtin_amdgcn_mfma_f32_32x32x16_bf16(a, b, c, 0, 0, 0);
}

__device__ __forceinline__ unsigned short tob(float x){
    unsigned u = __float_as_uint(x);
    return (unsigned short)((u + 0x7FFFu + ((u >> 16) & 1u)) >> 16);
}

// 16 named scalars — never an array, never address-taken: pure SSA for the allocator
struct PK16 {
    unsigned u0,u1,u2,u3,u4,u5,u6,u7,u8,u9,u10,u11,u12,u13,u14,u15;
};

struct alignas(16) SLDS {
    unsigned short cw2T[128*136];   // [i][k] = cw2[k][i]; col 128 = cb2
    unsigned short fwdWT[4][64*72]; // hw2..5: [i][k] = W[k][i]; col 64 = bias
    unsigned short bwdW[4][64*72];  // hw2..5 row-major [k_out][f]
    unsigned short hw1T[64*16];     // [i][k]: k0-3 = hw1[k][i], k4 = hb1[i]
    float c1pack[128*4];            // {cw1[0][k], cw1[1][k], cb1[k], 0}
    float cw3p[128*2];
    float hw1c[64*4];               // {hw1[0][f], hw1[1][f], hw1[2][f], hw1[3][f]}
    float hw6v[64];
    float cb3v[2];
    float pad[30];                  // tail guard (h=1 bias-step overreads see x0 operands)
};
// sizeof = 115072 B = 7192 uint4

#define FSTEP(st, a,b,c,d) { \
    unsigned x0=(a), x1=(b), x2=(c), x3=(d); \
    laneswap(x0, x2); laneswap(x1, x3); \
    bf16x8 bv = mkb(x0,x1,x2,x3); \
    const unsigned short* pp = W + col*72 + (st)*16 + h*8; \
    A0 = MF(ldA(pp),         bv, A0); \
    A1 = MF(ldA(pp + 32*72), bv, A1); }

// fwd layer 64->64: D = WT x B over 4 K-steps + bias K-step
__device__ __forceinline__ void fwd64(const unsigned short* W, PK16 p,
                                      f32x16& A0, f32x16& A1, int col, int h){
    A0 = zf(); A1 = zf();
    FSTEP(0, p.u0,  p.u1,  p.u2,  p.u3)
    FSTEP(1, p.u4,  p.u5,  p.u6,  p.u7)
    FSTEP(2, p.u8,  p.u9,  p.u10, p.u11)
    FSTEP(3, p.u12, p.u13, p.u14, p.u15)
    bf16x8 bb = mkb(h ? 0u : 0x3F80u, 0u, 0u, 0u);
    const unsigned short* pb = W + col*72 + 64 + h*8;
    A0 = MF(ldA(pb),         bb, A0);
    A1 = MF(ldA(pb + 32*72), bb, A1);
}

__device__ __forceinline__ void bwd64(const unsigned short* W, PK16 p,
                                      f32x16& A0, f32x16& A1, int col, int h){
    A0 = zf(); A1 = zf();
    FSTEP(0, p.u0,  p.u1,  p.u2,  p.u3)
    FSTEP(1, p.u4,  p.u5,  p.u6,  p.u7)
    FSTEP(2, p.u8,  p.u9,  p.u10, p.u11)
    FSTEP(3, p.u12, p.u13, p.u14, p.u15)
}
#undef FSTEP

// ---- named-member packing macros ----
#define RELU1(Z, i, DST, SH) { \
    float a = Z[2*(i)], b = Z[2*(i)+1]; \
    if (a > 0.f) m |= 1u << ((SH)+2*(i));   else a = 0.f; \
    if (b > 0.f) m |= 1u << ((SH)+2*(i)+1); else b = 0.f; \
    DST = cvtpk(a, b); }

#define RELU_ALL(Z0, Z1, MASK, P) { unsigned m = 0u; \
    RELU1(Z0,0,P.u0,0)  RELU1(Z0,1,P.u1,0)  RELU1(Z0,2,P.u2,0)  RELU1(Z0,3,P.u3,0) \
    RELU1(Z0,4,P.u4,0)  RELU1(Z0,5,P.u5,0)  RELU1(Z0,6,P.u6,0)  RELU1(Z0,7,P.u7,0) \
    RELU1(Z1,0,P.u8,16) RELU1(Z1,1,P.u9,16) RELU1(Z1,2,P.u10,16) RELU1(Z1,3,P.u11,16) \
    RELU1(Z1,4,P.u12,16) RELU1(Z1,5,P.u13,16) RELU1(Z1,6,P.u14,16) RELU1(Z1,7,P.u15,16) \
    MASK = m; }

#define TANH1(Z, i, DST) DST = cvtpk(fast_tanh(Z[2*(i)]), fast_tanh(Z[2*(i)+1]));
#define TANH_ALL(Z0, Z1, P) \
    TANH1(Z0,0,P.u0)  TANH1(Z0,1,P.u1)  TANH1(Z0,2,P.u2)  TANH1(Z0,3,P.u3) \
    TANH1(Z0,4,P.u4)  TANH1(Z0,5,P.u5)  TANH1(Z0,6,P.u6)  TANH1(Z0,7,P.u7) \
    TANH1(Z1,0,P.u8)  TANH1(Z1,1,P.u9)  TANH1(Z1,2,P.u10) TANH1(Z1,3,P.u11) \
    TANH1(Z1,4,P.u12) TANH1(Z1,5,P.u13) TANH1(Z1,6,P.u14) TANH1(Z1,7,P.u15)

#define RPK1(G, i, DST) DST = cvtpk(G[2*(i)], G[2*(i)+1]);
#define RPK_ALL(G0, G1, P) \
    RPK1(G0,0,P.u0)  RPK1(G0,1,P.u1)  RPK1(G0,2,P.u2)  RPK1(G0,3,P.u3) \
    RPK1(G0,4,P.u4)  RPK1(G0,5,P.u5)  RPK1(G0,6,P.u6)  RPK1(G0,7,P.u7) \
    RPK1(G1,0,P.u8)  RPK1(G1,1,P.u9)  RPK1(G1,2,P.u10) RPK1(G1,3,P.u11) \
    RPK1(G1,4,P.u12) RPK1(G1,5,P.u13) RPK1(G1,6,P.u14) RPK1(G1,7,P.u15)

#define TPR1(M, G, J) { \
    float tl = __uint_as_float((M) << 16); \
    float tH = __uint_as_float((M) & 0xFFFF0000u); \
    G[J]     *= fmaf(-tl, tl, 1.f); \
    G[(J)+1] *= fmaf(-tH, tH, 1.f); }

#define TPRIME_ALL(P) \
    TPR1(P.u0,g0,0)  TPR1(P.u1,g0,2)  TPR1(P.u2,g0,4)   TPR1(P.u3,g0,6) \
    TPR1(P.u4,g0,8)  TPR1(P.u5,g0,10) TPR1(P.u6,g0,12)  TPR1(P.u7,g0,14) \
    TPR1(P.u8,g1,0)  TPR1(P.u9,g1,2)  TPR1(P.u10,g1,4)  TPR1(P.u11,g1,6) \
    TPR1(P.u12,g1,8) TPR1(P.u13,g1,10) TPR1(P.u14,g1,12) TPR1(P.u15,g1,14)

// coupling net 2->125(relu)->125(tanh)->2, batch-in-lane-column MFMA form
__device__ __forceinline__ float2 couple(float u0f, float u1f, const SLDS* s, int col, int h){
    f32x16 c0 = zf(), c1 = zf(), c2 = zf(), c3 = zf();
#pragma unroll 2
    for (int st=0; st<8; ++st){
        int kb = st*16 + h*8;
        float4 cc0 = *(const float4*)&s->c1pack[4*(kb+0)];
        float4 cc1 = *(const float4*)&s->c1pack[4*(kb+1)];
        float4 cc2 = *(const float4*)&s->c1pack[4*(kb+2)];
        float4 cc3 = *(const float4*)&s->c1pack[4*(kb+3)];
        float4 cc4 = *(const float4*)&s->c1pack[4*(kb+4)];
        float4 cc5 = *(const float4*)&s->c1pack[4*(kb+5)];
        float4 cc6 = *(const float4*)&s->c1pack[4*(kb+6)];
        float4 cc7 = *(const float4*)&s->c1pack[4*(kb+7)];
        float h0 = fmaxf(fmaf(u1f, cc0.y, fmaf(u0f, cc0.x, cc0.z)), 0.f);
        float h1 = fmaxf(fmaf(u1f, cc1.y, fmaf(u0f, cc1.x, cc1.z)), 0.f);
        float h2 = fmaxf(fmaf(u1f, cc2.y, fmaf(u0f, cc2.x, cc2.z)), 0.f);
        float h3 = fmaxf(fmaf(u1f, cc3.y, fmaf(u0f, cc3.x, cc3.z)), 0.f);
        float h4 = fmaxf(fmaf(u1f, cc4.y, fmaf(u0f, cc4.x, cc4.z)), 0.f);
        float h5 = fmaxf(fmaf(u1f, cc5.y, fmaf(u0f, cc5.x, cc5.z)), 0.f);
        float h6 = fmaxf(fmaf(u1f, cc6.y, fmaf(u0f, cc6.x, cc6.z)), 0.f);
        float h7 = fmaxf(fmaf(u1f, cc7.y, fmaf(u0f, cc7.x, cc7.z)), 0.f);
        bf16x8 bv = mkb(cvtpk(h0,h1), cvtpk(h2,h3), cvtpk(h4,h5), cvtpk(h6,h7));
        const unsigned short* p = s->cw2T + col*136 + st*16 + h*8;
        c0 = MF(ldA(p),          bv, c0);
        c1 = MF(ldA(p + 32*136), bv, c1);
        c2 = MF(ldA(p + 64*136), bv, c2);
        c3 = MF(ldA(p + 96*136), bv, c3);
    }
    {   // bias K-step: B = {1,0,...} on h=0; A cols 128.. hold cb2
        bf16x8 bb = mkb(h ? 0u : 0x3F80u, 0u, 0u, 0u);
        const unsigned short* p = s->cw2T + col*136 + 128 + h*8;
        c0 = MF(ldA(p),          bb, c0);
        c1 = MF(ldA(p + 32*136), bb, c1);
        c2 = MF(ldA(p + 64*136), bb, c2);
        c3 = MF(ldA(p + 96*136), bb, c3);
    }
    float o0 = 0.f, o1 = 0.f;
#define CDOT(CA, T) \
    _Pragma("unroll") \
    for (int r=0; r<16; ++r){ \
        float t = fast_tanh(CA[r]); \
        int f = (T)*32 + (r>>2)*8 + (r&3) + h*4; \
        float2 wv = *(const float2*)&s->cw3p[2*f]; \
        o0 = fmaf(t, wv.x, o0); o1 = fmaf(t, wv.y, o1); }
    CDOT(c0,0) CDOT(c1,1) CDOT(c2,2) CDOT(c3,3)
#undef CDOT
    o0 = halfsum(o0);
    o1 = halfsum(o1);
    return make_float2(o0 + s->cb3v[0], o1 + s->cb3v[1]);
}

// one-shot: build the SLDS image in global workspace
__global__ void pack_ws(const float* __restrict__ cw1, const float* __restrict__ cb1,
                        const float* __restrict__ cw2, const float* __restrict__ cb2,
                        const float* __restrict__ cw3, const float* __restrict__ cb3,
                        const float* __restrict__ hw1, const float* __restrict__ hb1,
                        const float* __restrict__ hw2, const float* __restrict__ hb2,
                        const float* __restrict__ hw3, const float* __restrict__ hb3,
                        const float* __restrict__ hw4, const float* __restrict__ hb4,
                        const float* __restrict__ hw5, const float* __restrict__ hb5,
                        const float* __restrict__ hw6, SLDS* __restrict__ g){
    const int tid = blockIdx.x*256 + threadIdx.x;
    const int NT  = 64*256;
    for (int i = tid; i < 128*136; i += NT){
        int r = i/136, k = i%136;
        float v = 0.f;
        if (k < 125 && r < 125) v = cw2[k*125 + r];
        else if (k == 128 && r < 125) v = cb2[r];
        g->cw2T[i] = tob(v);
    }
#pragma unroll
    for (int m=0; m<4; ++m){
        const float* w = (m==0)?hw2:(m==1)?hw3:(m==2)?hw4:hw5;
        const float* b = (m==0)?hb2:(m==1)?hb3:(m==2)?hb4:hb5;
        for (int i = tid; i < 64*72; i += NT){
            int r = i/72, k = i%72;
            g->fwdWT[m][i] = tob((k<64) ? w[k*64 + r] : ((k==64) ? b[r] : 0.f));
            g->bwdW[m][i]  = tob((k<64) ? w[r*64 + k] : 0.f);
        }
    }
    for (int i = tid; i < 64*16; i += NT){
        int r = i/16, k = i%16;
        g->hw1T[i] = tob((k<4) ? hw1[k*64 + r] : ((k==4) ? hb1[r] : 0.f));
    }
    for (int k = tid; k < 128; k += NT){
        bool in = k < 125;
        g->c1pack[4*k+0] = in ? cw1[k]     : 0.f;
        g->c1pack[4*k+1] = in ? cw1[125+k] : 0.f;
        g->c1pack[4*k+2] = in ? cb1[k]     : 0.f;
        g->c1pack[4*k+3] = 0.f;
        g->cw3p[2*k+0]   = in ? cw3[2*k]   : 0.f;
        g->cw3p[2*k+1]   = in ? cw3[2*k+1] : 0.f;
    }
    for (int f = tid; f < 64; f += NT){
        g->hw1c[4*f+0] = hw1[f];
        g->hw1c[4*f+1] = hw1[64+f];
        g->hw1c[4*f+2] = hw1[128+f];
        g->hw1c[4*f+3] = hw1[192+f];
        g->hw6v[f] = hw6[f];
    }
    if (tid == 0){ g->cb3v[0] = cb3[0]; g->cb3v[1] = cb3[1]; }
    for (int i = tid; i < 30; i += NT) g->pad[i] = 0.f;
}

__global__ __launch_bounds__(512, 2) void pnn_mfma(
    const float* __restrict__ x, const SLDS* __restrict__ g,
    const float* __restrict__ S, const float* __restrict__ dt_q,
    const float* __restrict__ dt_p, const float* __restrict__ alpha_p,
    float* __restrict__ out)
{
    __shared__ SLDS s;
    const int tid = threadIdx.x;

    // stage SLDS image (16B copies)
    {
        const uint4* src = (const uint4*)g;
        uint4* dst = (uint4*)&s;
        for (int i = tid; i < (int)(sizeof(SLDS)/16); i += 512) dst[i] = src[i];
    }
    __syncthreads();

    const int lane = tid & 63;
    const int wv   = tid >> 6;
    const int col  = lane & 31;
    const int h    = lane >> 5;
    const int row  = blockIdx.x * 256 + wv*32 + col;

    float4 xv = ((const float4*)x)[row];

    float2 cpl = couple(xv.x, xv.y, &s, col, h);
    float th0 = xv.x, th1 = xv.y, th2 = xv.z + cpl.x, th3 = xv.w + cpl.y;

    // ---- H forward L1 (theta K=4 + bias slot, one K-step) ----
    f32x16 z0, z1;
    {
        bf16x8 b1 = mkb(h ? 0u : cvtpk(th0, th1),
                        h ? 0u : cvtpk(th2, th3),
                        h ? 0u : 0x3F80u, 0u);
        const unsigned short* p = s.hw1T + col*16 + h*8;
        z0 = MF(ldA(p),         b1, zf());
        z1 = MF(ldA(p + 32*16), b1, zf());
    }

    unsigned m1, m2;
    PK16 pkA, pk3, pk4, pkG;
    RELU_ALL(z0, z1, m1, pkA)

    fwd64(s.fwdWT[0], pkA, z0, z1, col, h);      // L2
    RELU_ALL(z0, z1, m2, pkA)

    fwd64(s.fwdWT[1], pkA, z0, z1, col, h);      // L3
    TANH_ALL(z0, z1, pk3)

    fwd64(s.fwdWT[2], pk3, z0, z1, col, h);      // L4
    TANH_ALL(z0, z1, pk4)

    fwd64(s.fwdWT[3], pk4, z0, z1, col, h);      // L5
    // g5 = hw6 ⊙ (1 - tanh(z5)^2)
#define G5Q(ZZ, T, q, MA, MB) { \
    float4 w6 = *(const float4*)&s.hw6v[(T)*32 + (q)*8 + h*4]; \
    float t0 = fast_tanh(ZZ[4*(q)+0]); float a0 = w6.x * fmaf(-t0,t0,1.f); \
    float t1 = fast_tanh(ZZ[4*(q)+1]); float a1 = w6.y * fmaf(-t1,t1,1.f); \
    float t2 = fast_tanh(ZZ[4*(q)+2]); float a2 = w6.z * fmaf(-t2,t2,1.f); \
    float t3 = fast_tanh(ZZ[4*(q)+3]); float a3 = w6.w * fmaf(-t3,t3,1.f); \
    MA = cvtpk(a0, a1); MB = cvtpk(a2, a3); }
    G5Q(z0,0,0,pkG.u0,pkG.u1)   G5Q(z0,0,1,pkG.u2,pkG.u3)
    G5Q(z0,0,2,pkG.u4,pkG.u5)   G5Q(z0,0,3,pkG.u6,pkG.u7)
    G5Q(z1,1,0,pkG.u8,pkG.u9)   G5Q(z1,1,1,pkG.u10,pkG.u11)
    G5Q(z1,1,2,pkG.u12,pkG.u13) G5Q(z1,1,3,pkG.u14,pkG.u15)
#undef G5Q

    // ---- backward ----
    f32x16 g0, g1;

    bwd64(s.bwdW[3], pkG, g0, g1, col, h);       // g4
    TPRIME_ALL(pk4)
    RPK_ALL(g0, g1, pkG)

    bwd64(s.bwdW[2], pkG, g0, g1, col, h);       // g3
    TPRIME_ALL(pk3)
    RPK_ALL(g0, g1, pkG)

    bwd64(s.bwdW[1], pkG, g0, g1, col, h);       // g2
#pragma unroll
    for (int r=0;r<16;++r){
        if (!((m2 >> r) & 1u))      g0[r] = 0.f;
        if (!((m2 >> (16+r)) & 1u)) g1[r] = 0.f;
    }
    RPK_ALL(g0, g1, pkG)

    bwd64(s.bwdW[0], pkG, g0, g1, col, h);       // g1
#pragma unroll
    for (int r=0;r<16;++r){
        if (!((m1 >> r) & 1u))      g0[r] = 0.f;
        if (!((m1 >> (16+r)) & 1u)) g1[r] = 0.f;
    }

    // dH = g1 @ hw1^T: per-lane partial over its 32 features, then cross-half add
    float dh0=0.f, dh1=0.f, dh2=0.f, dh3=0.f;
#define DHT(GG, T) \
    _Pragma("unroll") \
    for (int q=0;q<4;++q){ \
        int f0 = (T)*32 + q*8 + h*4; \
        _Pragma("unroll") \
        for (int m=0;m<4;++m){ \
            float4 wv4 = *(const float4*)&s.hw1c[4*(f0+m)]; \
            float gv = GG[4*q+m]; \
            dh0 = fmaf(gv, wv4.x, dh0); dh1 = fmaf(gv, wv4.y, dh1); \
            dh2 = fmaf(gv, wv4.z, dh2); dh3 = fmaf(gv, wv4.w, dh3); } }
    DHT(g0, 0)
    DHT(g1, 1)
#undef DHT
    dh0 = halfsum(dh0);
    dh1 = halfsum(dh1);
    dh2 = halfsum(dh2);
    dh3 = halfsum(dh3);

    // ---- epilogue ----
    float s01 = S[1] - S[4],  s02 = S[2]  - S[8],  s03 = S[3]  - S[12];
    float s10 = -s01,         s12 = S[6]  - S[9],  s13 = S[7]  - S[13];
    float s23 = S[11] - S[14];
    float s32 = -s23;

    float al = alpha_p[0], dq = dt_q[0], dp = dt_p[0];
    float r10 = th1 * s01 + th2 * s02 + th3 * s03;
    float r11 = th0 * s10 + th2 * s12 + th3 * s13;
    float r20 = th0 * s02 + th1 * s12 + th3 * s32;
    float r21 = th0 * s03 + th1 * s13 + th2 * s23;

    float dz10 =  dh2 * dq + al * r10;
    float dz11 =  dh3 * dq + al * r11;
    float dz20 = -dh0 * dp + al * r20;
    float dz21 = -dh1 * dp + al * r21;

    float p0 = th0 + 0.1f * dz10;
    float p1 = th1 + 0.1f * dz11;
    float p2 = th2 + 0.1f * dz20;
    float p3 = th3 + 0.1f * dz21;

    float2 d = couple(p0, p1, &s, col, h);

    if (h == 0)
        ((float4*)out)[row] = make_float4(p0, p1, p2 - d.x, p3 - d.y);
}

extern "C" void kernel_launch(void* const* d_in, const int* in_sizes, int n_in,
                              void* d_out, int out_size, void* d_ws, size_t ws_size,
                              hipStream_t stream) {
    (void)n_in; (void)out_size; (void)ws_size;
    const float* x   = (const float*)d_in[0];
    const float* cw1 = (const float*)d_in[1];
    const float* cb1 = (const float*)d_in[2];
    const float* cw2 = (const float*)d_in[3];
    const float* cb2 = (const float*)d_in[4];
    const float* cw3 = (const float*)d_in[5];
    const float* cb3 = (const float*)d_in[6];
    const float* hw1 = (const float*)d_in[7];
    const float* hb1 = (const float*)d_in[8];
    const float* hw2 = (const float*)d_in[9];
    const float* hb2 = (const float*)d_in[10];
    const float* hw3 = (const float*)d_in[11];
    const float* hb3 = (const float*)d_in[12];
    const float* hw4 = (const float*)d_in[13];
    const float* hb4 = (const float*)d_in[14];
    const float* hw5 = (const float*)d_in[15];
    const float* hb5 = (const float*)d_in[16];
    const float* hw6 = (const float*)d_in[17];
    const float* S   = (const float*)d_in[19];
    const float* dtq = (const float*)d_in[20];
    const float* dtp = (const float*)d_in[21];
    const float* al  = (const float*)d_in[22];
    float* out = (float*)d_out;
    SLDS* g   = (SLDS*)d_ws;
    int nrows = in_sizes[0] / 4;
    int grid  = nrows / 256;          // B = 524288 -> 2048 exact

    pack_ws<<<64, 256, 0, stream>>>(cw1, cb1, cw2, cb2, cw3, cb3, hw1, hb1,
                                    hw2, hb2, hw3, hb3, hw4, hb4, hw5, hb5, hw6, g);
    pnn_mfma<<<grid, 512, 0, stream>>>(x, g, S, dtq, dtp, al, out);
}

// Round 10
// 375.349 us; speedup vs baseline: 2.2547x; 1.0093x over previous
//
#include <hip/hip_runtime.h>

typedef __attribute__((ext_vector_type(16))) float    f32x16;
typedef __attribute__((ext_vector_type(8)))  short    bf16x8;
typedef __attribute__((ext_vector_type(2)))  int      i32x2;
typedef __attribute__((ext_vector_type(4)))  unsigned u32x4;

// compiler-managed permlane32_swap: a' = {a.lo, b.lo}, b' = {a.hi, b.hi}
__device__ __forceinline__ void laneswap(unsigned& a, unsigned& b){
    i32x2 r = __builtin_amdgcn_permlane32_swap((int)a, (int)b, false, false);
    a = (unsigned)r[0]; b = (unsigned)r[1];
}

// pack two floats into {bf16(lo), bf16(hi)<<16}, RNE
__device__ __forceinline__ unsigned cvtpk(float lo, float hi){
    unsigned ul = __float_as_uint(lo);
    unsigned uh = __float_as_uint(hi);
    ul = (ul + 0x7FFFu + ((ul >> 16) & 1u)) >> 16;
    uh = (uh + 0x7FFFu + ((uh >> 16) & 1u)) & 0xFFFF0000u;
    return ul | uh;
}

__device__ __forceinline__ float halfsum(float v){   // v + (other 32-lane half)
    return v + __shfl_xor(v, 32, 64);
}

__device__ __forceinline__ float fast_tanh(float v){
    float vc = fminf(v, 15.0f);
    float e  = __expf(vc + vc);
    float r  = __builtin_amdgcn_rcpf(e + 1.0f);
    return (e - 1.0f) * r;
}

// SSA-clean B-operand construction
__device__ __forceinline__ bf16x8 mkb(unsigned a, unsigned b, unsigned c, unsigned d){
    u32x4 t; t[0]=a; t[1]=b; t[2]=c; t[3]=d;
    return __builtin_bit_cast(bf16x8, t);
}

__device__ __forceinline__ f32x16 zf(){
    f32x16 z;
#pragma unroll
    for (int i=0;i<16;++i) z[i]=0.f;
    return z;
}

__device__ __forceinline__ bf16x8 ldA(const unsigned short* p){
    return *(const bf16x8*)p;   // 16B-aligned ds_read_b128
}

__device__ __forceinline__ f32x16 MF(bf16x8 a, bf16x8 b, f32x16 c){
    return __builtin_amdgcn_mfma_f32_32x32x16_bf16(a, b, c, 0, 0, 0);
}

__device__ __forceinline__ unsigned short tob(float x){
    unsigned u = __float_as_uint(x);
    return (unsigned short)((u + 0x7FFFu + ((u >> 16) & 1u)) >> 16);
}

// 16 named scalars — never an array, never address-taken: pure SSA for the allocator
struct PK16 {
    unsigned u0,u1,u2,u3,u4,u5,u6,u7,u8,u9,u10,u11,u12,u13,u14,u15;
};

struct alignas(16) SLDS {
    unsigned short cw2T[128*136];   // [i][k] = cw2[k][i]; col 128 = cb2
    unsigned short fwdWT[4][64*72]; // hw2..5: [i][k] = W[k][i]; col 64 = bias
    unsigned short bwdW[4][64*72];  // hw2..5 row-major [k_out][f]
    unsigned short hw1T[64*16];     // [i][k]: k0-3 = hw1[k][i], k4 = hb1[i]
    float c1pack[128*4];            // {cw1[0][k], cw1[1][k], cb1[k], 0}
    float cw3p[128*2];
    float hw1c[64*4];               // {hw1[0][f], hw1[1][f], hw1[2][f], hw1[3][f]}
    float hw6v[64];
    float cb3v[2];
    float pad[30];                  // tail guard (h=1 bias-step overreads see x0 operands)
};
// sizeof = 115072 B = 7192 uint4

#define FSTEP(st, a,b,c,d) { \
    unsigned x0=(a), x1=(b), x2=(c), x3=(d); \
    laneswap(x0, x2); laneswap(x1, x3); \
    bf16x8 bv = mkb(x0,x1,x2,x3); \
    const unsigned short* pp = W + col*72 + (st)*16 + h*8; \
    A0 = MF(ldA(pp),         bv, A0); \
    A1 = MF(ldA(pp + 32*72), bv, A1); }

// fwd layer 64->64: D = WT x B over 4 K-steps + bias K-step
__device__ __forceinline__ void fwd64(const unsigned short* W, PK16 p,
                                      f32x16& A0, f32x16& A1, int col, int h){
    A0 = zf(); A1 = zf();
    FSTEP(0, p.u0,  p.u1,  p.u2,  p.u3)
    FSTEP(1, p.u4,  p.u5,  p.u6,  p.u7)
    FSTEP(2, p.u8,  p.u9,  p.u10, p.u11)
    FSTEP(3, p.u12, p.u13, p.u14, p.u15)
    bf16x8 bb = mkb(h ? 0u : 0x3F80u, 0u, 0u, 0u);
    const unsigned short* pb = W + col*72 + 64 + h*8;
    A0 = MF(ldA(pb),         bb, A0);
    A1 = MF(ldA(pb + 32*72), bb, A1);
}

__device__ __forceinline__ void bwd64(const unsigned short* W, PK16 p,
                                      f32x16& A0, f32x16& A1, int col, int h){
    A0 = zf(); A1 = zf();
    FSTEP(0, p.u0,  p.u1,  p.u2,  p.u3)
    FSTEP(1, p.u4,  p.u5,  p.u6,  p.u7)
    FSTEP(2, p.u8,  p.u9,  p.u10, p.u11)
    FSTEP(3, p.u12, p.u13, p.u14, p.u15)
}
#undef FSTEP

// ---- named-member packing macros ----
#define RELU1(Z, i, DST, SH) { \
    float a = Z[2*(i)], b = Z[2*(i)+1]; \
    if (a > 0.f) m |= 1u << ((SH)+2*(i));   else a = 0.f; \
    if (b > 0.f) m |= 1u << ((SH)+2*(i)+1); else b = 0.f; \
    DST = cvtpk(a, b); }

#define RELU_ALL(Z0, Z1, MASK, P) { unsigned m = 0u; \
    RELU1(Z0,0,P.u0,0)  RELU1(Z0,1,P.u1,0)  RELU1(Z0,2,P.u2,0)  RELU1(Z0,3,P.u3,0) \
    RELU1(Z0,4,P.u4,0)  RELU1(Z0,5,P.u5,0)  RELU1(Z0,6,P.u6,0)  RELU1(Z0,7,P.u7,0) \
    RELU1(Z1,0,P.u8,16) RELU1(Z1,1,P.u9,16) RELU1(Z1,2,P.u10,16) RELU1(Z1,3,P.u11,16) \
    RELU1(Z1,4,P.u12,16) RELU1(Z1,5,P.u13,16) RELU1(Z1,6,P.u14,16) RELU1(Z1,7,P.u15,16) \
    MASK = m; }

#define TANH1(Z, i, DST) DST = cvtpk(fast_tanh(Z[2*(i)]), fast_tanh(Z[2*(i)+1]));
#define TANH_ALL(Z0, Z1, P) \
    TANH1(Z0,0,P.u0)  TANH1(Z0,1,P.u1)  TANH1(Z0,2,P.u2)  TANH1(Z0,3,P.u3) \
    TANH1(Z0,4,P.u4)  TANH1(Z0,5,P.u5)  TANH1(Z0,6,P.u6)  TANH1(Z0,7,P.u7) \
    TANH1(Z1,0,P.u8)  TANH1(Z1,1,P.u9)  TANH1(Z1,2,P.u10) TANH1(Z1,3,P.u11) \
    TANH1(Z1,4,P.u12) TANH1(Z1,5,P.u13) TANH1(Z1,6,P.u14) TANH1(Z1,7,P.u15)

#define RPK1(G, i, DST) DST = cvtpk(G[2*(i)], G[2*(i)+1]);
#define RPK_ALL(G0, G1, P) \
    RPK1(G0,0,P.u0)  RPK1(G0,1,P.u1)  RPK1(G0,2,P.u2)  RPK1(G0,3,P.u3) \
    RPK1(G0,4,P.u4)  RPK1(G0,5,P.u5)  RPK1(G0,6,P.u6)  RPK1(G0,7,P.u7) \
    RPK1(G1,0,P.u8)  RPK1(G1,1,P.u9)  RPK1(G1,2,P.u10) RPK1(G1,3,P.u11) \
    RPK1(G1,4,P.u12) RPK1(G1,5,P.u13) RPK1(G1,6,P.u14) RPK1(G1,7,P.u15)

#define TPR1(M, G, J) { \
    float tl = __uint_as_float((M) << 16); \
    float tH = __uint_as_float((M) & 0xFFFF0000u); \
    G[J]     *= fmaf(-tl, tl, 1.f); \
    G[(J)+1] *= fmaf(-tH, tH, 1.f); }

#define TPRIME_ALL(P) \
    TPR1(P.u0,g0,0)  TPR1(P.u1,g0,2)  TPR1(P.u2,g0,4)   TPR1(P.u3,g0,6) \
    TPR1(P.u4,g0,8)  TPR1(P.u5,g0,10) TPR1(P.u6,g0,12)  TPR1(P.u7,g0,14) \
    TPR1(P.u8,g1,0)  TPR1(P.u9,g1,2)  TPR1(P.u10,g1,4)  TPR1(P.u11,g1,6) \
    TPR1(P.u12,g1,8) TPR1(P.u13,g1,10) TPR1(P.u14,g1,12) TPR1(P.u15,g1,14)

// coupling net 2->125(relu)->125(tanh)->2, batch-in-lane-column MFMA form
__device__ __forceinline__ float2 couple(float u0f, float u1f, const SLDS* s, int col, int h){
    f32x16 c0 = zf(), c1 = zf(), c2 = zf(), c3 = zf();
#pragma unroll 2
    for (int st=0; st<8; ++st){
        int kb = st*16 + h*8;
        float4 cc0 = *(const float4*)&s->c1pack[4*(kb+0)];
        float4 cc1 = *(const float4*)&s->c1pack[4*(kb+1)];
        float4 cc2 = *(const float4*)&s->c1pack[4*(kb+2)];
        float4 cc3 = *(const float4*)&s->c1pack[4*(kb+3)];
        float4 cc4 = *(const float4*)&s->c1pack[4*(kb+4)];
        float4 cc5 = *(const float4*)&s->c1pack[4*(kb+5)];
        float4 cc6 = *(const float4*)&s->c1pack[4*(kb+6)];
        float4 cc7 = *(const float4*)&s->c1pack[4*(kb+7)];
        float h0 = fmaxf(fmaf(u1f, cc0.y, fmaf(u0f, cc0.x, cc0.z)), 0.f);
        float h1 = fmaxf(fmaf(u1f, cc1.y, fmaf(u0f, cc1.x, cc1.z)), 0.f);
        float h2 = fmaxf(fmaf(u1f, cc2.y, fmaf(u0f, cc2.x, cc2.z)), 0.f);
        float h3 = fmaxf(fmaf(u1f, cc3.y, fmaf(u0f, cc3.x, cc3.z)), 0.f);
        float h4 = fmaxf(fmaf(u1f, cc4.y, fmaf(u0f, cc4.x, cc4.z)), 0.f);
        float h5 = fmaxf(fmaf(u1f, cc5.y, fmaf(u0f, cc5.x, cc5.z)), 0.f);
        float h6 = fmaxf(fmaf(u1f, cc6.y, fmaf(u0f, cc6.x, cc6.z)), 0.f);
        float h7 = fmaxf(fmaf(u1f, cc7.y, fmaf(u0f, cc7.x, cc7.z)), 0.f);
        bf16x8 bv = mkb(cvtpk(h0,h1), cvtpk(h2,h3), cvtpk(h4,h5), cvtpk(h6,h7));
        const unsigned short* p = s->cw2T + col*136 + st*16 + h*8;
        c0 = MF(ldA(p),          bv, c0);
        c1 = MF(ldA(p + 32*136), bv, c1);
        c2 = MF(ldA(p + 64*136), bv, c2);
        c3 = MF(ldA(p + 96*136), bv, c3);
    }
    {   // bias K-step: B = {1,0,...} on h=0; A cols 128.. hold cb2
        bf16x8 bb = mkb(h ? 0u : 0x3F80u, 0u, 0u, 0u);
        const unsigned short* p = s->cw2T + col*136 + 128 + h*8;
        c0 = MF(ldA(p),          bb, c0);
        c1 = MF(ldA(p + 32*136), bb, c1);
        c2 = MF(ldA(p + 64*136), bb, c2);
        c3 = MF(ldA(p + 96*136), bb, c3);
    }
    float o0 = 0.f, o1 = 0.f;
#define CDOT(CA, T) \
    _Pragma("unroll") \
    for (int r=0; r<16; ++r){ \
        float t = fast_tanh(CA[r]); \
        int f = (T)*32 + (r>>2)*8 + (r&3) + h*4; \
        float2 wv = *(const float2*)&s->cw3p[2*f]; \
        o0 = fmaf(t, wv.x, o0); o1 = fmaf(t, wv.y, o1); }
    CDOT(c0,0) CDOT(c1,1) CDOT(c2,2) CDOT(c3,3)
#undef CDOT
    o0 = halfsum(o0);
    o1 = halfsum(o1);
    return make_float2(o0 + s->cb3v[0], o1 + s->cb3v[1]);
}

// one-shot: build the SLDS image in global workspace
__global__ void pack_ws(const float* __restrict__ cw1, const float* __restrict__ cb1,
                        const float* __restrict__ cw2, const float* __restrict__ cb2,
                        const float* __restrict__ cw3, const float* __restrict__ cb3,
                        const float* __restrict__ hw1, const float* __restrict__ hb1,
                        const float* __restrict__ hw2, const float* __restrict__ hb2,
                        const float* __restrict__ hw3, const float* __restrict__ hb3,
                        const float* __restrict__ hw4, const float* __restrict__ hb4,
                        const float* __restrict__ hw5, const float* __restrict__ hb5,
                        const float* __restrict__ hw6, SLDS* __restrict__ g){
    const int tid = blockIdx.x*256 + threadIdx.x;
    const int NT  = 64*256;
    for (int i = tid; i < 128*136; i += NT){
        int r = i/136, k = i%136;
        float v = 0.f;
        if (k < 125 && r < 125) v = cw2[k*125 + r];
        else if (k == 128 && r < 125) v = cb2[r];
        g->cw2T[i] = tob(v);
    }
#pragma unroll
    for (int m=0; m<4; ++m){
        const float* w = (m==0)?hw2:(m==1)?hw3:(m==2)?hw4:hw5;
        const float* b = (m==0)?hb2:(m==1)?hb3:(m==2)?hb4:hb5;
        for (int i = tid; i < 64*72; i += NT){
            int r = i/72, k = i%72;
            g->fwdWT[m][i] = tob((k<64) ? w[k*64 + r] : ((k==64) ? b[r] : 0.f));
            g->bwdW[m][i]  = tob((k<64) ? w[r*64 + k] : 0.f);
        }
    }
    for (int i = tid; i < 64*16; i += NT){
        int r = i/16, k = i%16;
        g->hw1T[i] = tob((k<4) ? hw1[k*64 + r] : ((k==4) ? hb1[r] : 0.f));
    }
    for (int k = tid; k < 128; k += NT){
        bool in = k < 125;
        g->c1pack[4*k+0] = in ? cw1[k]     : 0.f;
        g->c1pack[4*k+1] = in ? cw1[125+k] : 0.f;
        g->c1pack[4*k+2] = in ? cb1[k]     : 0.f;
        g->c1pack[4*k+3] = 0.f;
        g->cw3p[2*k+0]   = in ? cw3[2*k]   : 0.f;
        g->cw3p[2*k+1]   = in ? cw3[2*k+1] : 0.f;
    }
    for (int f = tid; f < 64; f += NT){
        g->hw1c[4*f+0] = hw1[f];
        g->hw1c[4*f+1] = hw1[64+f];
        g->hw1c[4*f+2] = hw1[128+f];
        g->hw1c[4*f+3] = hw1[192+f];
        g->hw6v[f] = hw6[f];
    }
    if (tid == 0){ g->cb3v[0] = cb3[0]; g->cb3v[1] = cb3[1]; }
    for (int i = tid; i < 30; i += NT) g->pad[i] = 0.f;
}

// (512,1): 512-unified-reg budget per wave. LDS (115KB -> 1 block/CU) caps
// occupancy at 8 waves/CU regardless; let the allocator take what it needs
// instead of spilling ~112 dwords/thread to scratch (r9: WRITE_SIZE 448 MB).
__global__ __launch_bounds__(512, 1) void pnn_mfma(
    const float* __restrict__ x, const SLDS* __restrict__ g,
    const float* __restrict__ S, const float* __restrict__ dt_q,
    const float* __restrict__ dt_p, const float* __restrict__ alpha_p,
    float* __restrict__ out)
{
    __shared__ SLDS s;
    const int tid = threadIdx.x;

    // stage SLDS image (16B copies)
    {
        const uint4* src = (const uint4*)g;
        uint4* dst = (uint4*)&s;
        for (int i = tid; i < (int)(sizeof(SLDS)/16); i += 512) dst[i] = src[i];
    }
    __syncthreads();

    const int lane = tid & 63;
    const int wv   = tid >> 6;
    const int col  = lane & 31;
    const int h    = lane >> 5;
    const int row  = blockIdx.x * 256 + wv*32 + col;

    float4 xv = ((const float4*)x)[row];

    float2 cpl = couple(xv.x, xv.y, &s, col, h);
    float th0 = xv.x, th1 = xv.y, th2 = xv.z + cpl.x, th3 = xv.w + cpl.y;

    // ---- H forward L1 (theta K=4 + bias slot, one K-step) ----
    f32x16 z0, z1;
    {
        bf16x8 b1 = mkb(h ? 0u : cvtpk(th0, th1),
                        h ? 0u : cvtpk(th2, th3),
                        h ? 0u : 0x3F80u, 0u);
        const unsigned short* p = s.hw1T + col*16 + h*8;
        z0 = MF(ldA(p),         b1, zf());
        z1 = MF(ldA(p + 32*16), b1, zf());
    }

    unsigned m1, m2;
    PK16 pkA, pk3, pk4, pkG;
    RELU_ALL(z0, z1, m1, pkA)

    fwd64(s.fwdWT[0], pkA, z0, z1, col, h);      // L2
    RELU_ALL(z0, z1, m2, pkA)

    fwd64(s.fwdWT[1], pkA, z0, z1, col, h);      // L3
    TANH_ALL(z0, z1, pk3)

    fwd64(s.fwdWT[2], pk3, z0, z1, col, h);      // L4
    TANH_ALL(z0, z1, pk4)

    fwd64(s.fwdWT[3], pk4, z0, z1, col, h);      // L5
    // g5 = hw6 ⊙ (1 - tanh(z5)^2)
#define G5Q(ZZ, T, q, MA, MB) { \
    float4 w6 = *(const float4*)&s.hw6v[(T)*32 + (q)*8 + h*4]; \
    float t0 = fast_tanh(ZZ[4*(q)+0]); float a0 = w6.x * fmaf(-t0,t0,1.f); \
    float t1 = fast_tanh(ZZ[4*(q)+1]); float a1 = w6.y * fmaf(-t1,t1,1.f); \
    float t2 = fast_tanh(ZZ[4*(q)+2]); float a2 = w6.z * fmaf(-t2,t2,1.f); \
    float t3 = fast_tanh(ZZ[4*(q)+3]); float a3 = w6.w * fmaf(-t3,t3,1.f); \
    MA = cvtpk(a0, a1); MB = cvtpk(a2, a3); }
    G5Q(z0,0,0,pkG.u0,pkG.u1)   G5Q(z0,0,1,pkG.u2,pkG.u3)
    G5Q(z0,0,2,pkG.u4,pkG.u5)   G5Q(z0,0,3,pkG.u6,pkG.u7)
    G5Q(z1,1,0,pkG.u8,pkG.u9)   G5Q(z1,1,1,pkG.u10,pkG.u11)
    G5Q(z1,1,2,pkG.u12,pkG.u13) G5Q(z1,1,3,pkG.u14,pkG.u15)
#undef G5Q

    // ---- backward ----
    f32x16 g0, g1;

    bwd64(s.bwdW[3], pkG, g0, g1, col, h);       // g4
    TPRIME_ALL(pk4)
    RPK_ALL(g0, g1, pkG)

    bwd64(s.bwdW[2], pkG, g0, g1, col, h);       // g3
    TPRIME_ALL(pk3)
    RPK_ALL(g0, g1, pkG)

    bwd64(s.bwdW[1], pkG, g0, g1, col, h);       // g2
#pragma unroll
    for (int r=0;r<16;++r){
        if (!((m2 >> r) & 1u))      g0[r] = 0.f;
        if (!((m2 >> (16+r)) & 1u)) g1[r] = 0.f;
    }
    RPK_ALL(g0, g1, pkG)

    bwd64(s.bwdW[0], pkG, g0, g1, col, h);       // g1
#pragma unroll
    for (int r=0;r<16;++r){
        if (!((m1 >> r) & 1u))      g0[r] = 0.f;
        if (!((m1 >> (16+r)) & 1u)) g1[r] = 0.f;
    }

    // dH = g1 @ hw1^T: per-lane partial over its 32 features, then cross-half add
    float dh0=0.f, dh1=0.f, dh2=0.f, dh3=0.f;
#define DHT(GG, T) \
    _Pragma("unroll") \
    for (int q=0;q<4;++q){ \
        int f0 = (T)*32 + q*8 + h*4; \
        _Pragma("unroll") \
        for (int m=0;m<4;++m){ \
            float4 wv4 = *(const float4*)&s.hw1c[4*(f0+m)]; \
            float gv = GG[4*q+m]; \
            dh0 = fmaf(gv, wv4.x, dh0); dh1 = fmaf(gv, wv4.y, dh1); \
            dh2 = fmaf(gv, wv4.z, dh2); dh3 = fmaf(gv, wv4.w, dh3); } }
    DHT(g0, 0)
    DHT(g1, 1)
#undef DHT
    dh0 = halfsum(dh0);
    dh1 = halfsum(dh1);
    dh2 = halfsum(dh2);
    dh3 = halfsum(dh3);

    // ---- epilogue ----
    float s01 = S[1] - S[4],  s02 = S[2]  - S[8],  s03 = S[3]  - S[12];
    float s10 = -s01,         s12 = S[6]  - S[9],  s13 = S[7]  - S[13];
    float s23 = S[11] - S[14];
    float s32 = -s23;

    float al = alpha_p[0], dq = dt_q[0], dp = dt_p[0];
    float r10 = th1 * s01 + th2 * s02 + th3 * s03;
    float r11 = th0 * s10 + th2 * s12 + th3 * s13;
    float r20 = th0 * s02 + th1 * s12 + th3 * s32;
    float r21 = th0 * s03 + th1 * s13 + th2 * s23;

    float dz10 =  dh2 * dq + al * r10;
    float dz11 =  dh3 * dq + al * r11;
    float dz20 = -dh0 * dp + al * r20;
    float dz21 = -dh1 * dp + al * r21;

    float p0 = th0 + 0.1f * dz10;
    float p1 = th1 + 0.1f * dz11;
    float p2 = th2 + 0.1f * dz20;
    float p3 = th3 + 0.1f * dz21;

    float2 d = couple(p0, p1, &s, col, h);

    if (h == 0)
        ((float4*)out)[row] = make_float4(p0, p1, p2 - d.x, p3 - d.y);
}

extern "C" void kernel_launch(void* const* d_in, const int* in_sizes, int n_in,
                              void* d_out, int out_size, void* d_ws, size_t ws_size,
                              hipStream_t stream) {
    (void)n_in; (void)out_size; (void)ws_size;
    const float* x   = (const float*)d_in[0];
    const float* cw1 = (const float*)d_in[1];
    const float* cb1 = (const float*)d_in[2];
    const float* cw2 = (const float*)d_in[3];
    const float* cb2 = (const float*)d_in[4];
    const float* cw3 = (const float*)d_in[5];
    const float* cb3 = (const float*)d_in[6];
    const float* hw1 = (const float*)d_in[7];
    const float* hb1 = (const float*)d_in[8];
    const float* hw2 = (const float*)d_in[9];
    const float* hb2 = (const float*)d_in[10];
    const float* hw3 = (const float*)d_in[11];
    const float* hb3 = (const float*)d_in[12];
    const float* hw4 = (const float*)d_in[13];
    const float* hb4 = (const float*)d_in[14];
    const float* hw5 = (const float*)d_in[15];
    const float* hb5 = (const float*)d_in[16];
    const float* hw6 = (const float*)d_in[17];
    const float* S   = (const float*)d_in[19];
    const float* dtq = (const float*)d_in[20];
    const float* dtp = (const float*)d_in[21];
    const float* al  = (const float*)d_in[22];
    float* out = (float*)d_out;
    SLDS* g   = (SLDS*)d_ws;
    int nrows = in_sizes[0] / 4;
    int grid  = nrows / 256;          // B = 524288 -> 2048 exact

    pack_ws<<<64, 256, 0, stream>>>(cw1, cb1, cw2, cb2, cw3, cb3, hw1, hb1,
                                    hw2, hb2, hw3, hb3, hw4, hb4, hw5, hb5, hw6, g);
    pnn_mfma<<<grid, 512, 0, stream>>>(x, g, S, dtq, dtp, al, out);
}